// Round 9
// baseline (520.457 us; speedup 1.0000x reference)
//
#include <hip/hip_runtime.h>
#include <hip/hip_bf16.h>
#include <stdint.h>

#define B_ 4096
#define D_ 2048
#define U_ 2048
#define K_ 4096   // D + U
#define N_ 8192   // 4 * U

typedef __bf16 bf16x8 __attribute__((ext_vector_type(8)));
typedef float floatx4 __attribute__((ext_vector_type(4)));
typedef unsigned short ushort8 __attribute__((ext_vector_type(8)));

__device__ __forceinline__ unsigned short f2bf(float f) {
    union { float f; unsigned int u; } v; v.f = f;
    unsigned int u = v.u;
    unsigned int r = (u + 0x7fffu + ((u >> 16) & 1u)) >> 16;  // round-nearest-even
    return (unsigned short)r;
}

__device__ __forceinline__ float bf2f(unsigned short b) {
    union { unsigned int u; float f; } v;
    v.u = ((unsigned int)b) << 16;
    return v.f;
}

__device__ __forceinline__ float sigmoid_(float x) {
    return 1.0f / (1.0f + __expf(-x));
}
__device__ __forceinline__ float tanh_(float x) {
    return 1.0f - 2.0f / (__expf(2.0f * x) + 1.0f);
}

// ---------------------------------------------------------------------------
// Kernel 1: pack [x | h] -> Abf[4096][4096] bf16 (row-major, K contiguous)
// ---------------------------------------------------------------------------
__global__ void k_convA(const float* __restrict__ x, const float* __restrict__ h,
                        unsigned short* __restrict__ Abf) {
    int t = blockIdx.x * blockDim.x + threadIdx.x;   // one float4 each
    long e = (long)t * 4;
    int b = (int)(e >> 12);       // / 4096
    int k = (int)(e & 4095);
    const float* src = (k < D_) ? (x + (size_t)b * D_ + k)
                                : (h + (size_t)b * U_ + (k - D_));
    float4 v = *(const float4*)src;
    ushort4 o;
    o.x = f2bf(v.x); o.y = f2bf(v.y); o.z = f2bf(v.z); o.w = f2bf(v.w);
    *(ushort4*)(Abf + e) = o;
}

// ---------------------------------------------------------------------------
// Kernel 2: transpose weights -> Bt[8192][4096] bf16 (plain: row = g*2048+u)
// ---------------------------------------------------------------------------
__global__ __launch_bounds__(256) void k_convB(
        const float* __restrict__ Wx0, const float* __restrict__ Wx1,
        const float* __restrict__ Wx2, const float* __restrict__ Wx3,
        const float* __restrict__ Wh0, const float* __restrict__ Wh1,
        const float* __restrict__ Wh2, const float* __restrict__ Wh3,
        unsigned short* __restrict__ Bt) {
    __shared__ float tile[64][65];   // +1 pad: <=2-way (free) conflicts
    const int g  = blockIdx.z;
    const int k0 = blockIdx.x * 64;
    const int u0 = blockIdx.y * 64;
    const int t  = threadIdx.x;
    const float* W;
    if (k0 < D_) {
        W = (g == 0 ? Wx0 : g == 1 ? Wx1 : g == 2 ? Wx2 : Wx3) + (size_t)k0 * U_;
    } else {
        W = (g == 0 ? Wh0 : g == 1 ? Wh1 : g == 2 ? Wh2 : Wh3) + (size_t)(k0 - D_) * U_;
    }
    {
        const int kr_b = t >> 4;          // 0..15
        const int uc   = (t & 15) * 4;    // 0..60
        #pragma unroll
        for (int p = 0; p < 4; ++p) {
            int kr = p * 16 + kr_b;
            float4 v = *(const float4*)(W + (size_t)kr * U_ + u0 + uc);
            tile[kr][uc + 0] = v.x;
            tile[kr][uc + 1] = v.y;
            tile[kr][uc + 2] = v.z;
            tile[kr][uc + 3] = v.w;
        }
    }
    __syncthreads();
    {
        const int kc = (t & 7) * 8;       // 0..56
        #pragma unroll
        for (int p = 0; p < 2; ++p) {
            int u_idx = p * 32 + (t >> 3);          // 0..63
            int u = u0 + u_idx;
            int nrow = g * U_ + u;                   // plain mapping
            ushort8 o;
            #pragma unroll
            for (int kk = 0; kk < 8; ++kk)
                o[kk] = f2bf(tile[kc + kk][u_idx]);
            *(ushort8*)(Bt + (size_t)nrow * K_ + k0 + kc) = o;
        }
    }
}

// ---------------------------------------------------------------------------
// Kernel 3: GEMM — 256x256 tile, 8 waves, BK=32, 2-buffer LDS (64 KB).
// R9 change: FRAGMENT double-buffer. R8 measured 2250 cyc/tile =
// LDS-read window (1156) SERIAL with MFMA window (1242) — the lockstep
// barrier made all 96 ds_reads flood the pipe, MFMAs gated on own reads.
// Now: per tile, read NEXT tile's frags into the other register set while
// THIS tile's 32 MFMAs run ungated. Reads drain under the MFMA window.
//   body(t): stage(t+2 -> buf[t&1]); ds_read frags(t+1 from buf[(t+1)&1])
//            -> other set; MFMA(t, this set); lgkmcnt(0); vmcnt(0); barrier
// lgkm0/vmcnt0 are ~free (issued ~1242 cyc earlier) and keep the proven
// own-waits-before-barrier visibility chain. Even/odd unroll gives static
// register sets + static buffer parity (rule #20). sched_group_barrier
// pins 12 DS_READs before 32 MFMAs so the scheduler can't sink the reads.
// T2 swizzle (conflicts 0, R7-verified), T5 setprio, T1 XCD swizzle kept.
// ---------------------------------------------------------------------------
__device__ __forceinline__ void gload16(const unsigned short* g, unsigned short* l) {
    __builtin_amdgcn_global_load_lds(
        (const __attribute__((address_space(1))) void*)g,
        (__attribute__((address_space(3))) void*)l, 16, 0, 0);
}

#define BARRIER() __builtin_amdgcn_s_barrier()

#define STAGE(BUFBASE, KT) do { \
    gload16(gA0 + (KT), (BUFBASE)); \
    gload16(gA1 + (KT), (BUFBASE) + 4096); \
    gload16(gB0 + (KT), (BUFBASE) + 8192); \
    gload16(gB1 + (KT), (BUFBASE) + 12288); \
} while (0)

#define READ_FRAGS(SBASE, AQ, BQ) do { \
    _Pragma("unroll") \
    for (int j_ = 0; j_ < 4; ++j_) BQ[j_] = *(const bf16x8*)((SBASE) + bBase + j_ * 512); \
    _Pragma("unroll") \
    for (int i_ = 0; i_ < 8; ++i_) AQ[i_] = *(const bf16x8*)((SBASE) + aBase + i_ * 512); \
} while (0)

#define MFMA_ALL(AQ, BQ) do { \
    _Pragma("unroll") \
    for (int i_ = 0; i_ < 8; ++i_) \
        _Pragma("unroll") \
        for (int j_ = 0; j_ < 4; ++j_) \
            acc[i_][j_] = __builtin_amdgcn_mfma_f32_16x16x32_bf16( \
                AQ[i_], BQ[j_], acc[i_][j_], 0, 0, 0); \
} while (0)

#define PIN_SCHED() do { \
    __builtin_amdgcn_sched_group_barrier(0x100, 12, 0); /* DS_READ x12 first */ \
    __builtin_amdgcn_sched_group_barrier(0x008, 32, 0); /* then MFMA x32    */ \
} while (0)

#define BODY_WAITS() do { \
    asm volatile("s_waitcnt lgkmcnt(0)" ::: "memory"); \
    asm volatile("s_waitcnt vmcnt(0)" ::: "memory"); \
    BARRIER(); \
} while (0)

__global__ __launch_bounds__(512, 2) void k_gemm(const unsigned short* __restrict__ A,
                                                 const unsigned short* __restrict__ Bt,
                                                 unsigned short* __restrict__ Z) {
    __shared__ __align__(16) unsigned short sm[2 * 16384];   // 64 KB: 2 bufs

    // T1: XCD-contiguous chunks; nwg=512, divisible by 8 -> simple swizzle valid
    const int id  = blockIdx.x;
    const int swz = (id & 7) * 64 + (id >> 3);
    const int m0  = (swz & 15) << 8;              // 16 m-blocks
    const int n0  = (swz >> 4) << 8;              // 32 n-blocks

    const int tid  = threadIdx.x;
    const int w    = tid >> 6;        // wave 0..7
    const int l    = tid & 63;
    const int wr   = w >> 2;          // 0..1  (M)
    const int wc   = w & 3;           // 0..3  (N)
    const int r    = l & 15;
    const int quad = l >> 4;
    // T2 read-side swizzle: granule' = quad ^ ((row>>1)&3); row has 16-aligned
    // prefix + r, so (row>>1)&3 == (r>>1)&3 — per-lane constant.
    const int sw8  = (quad ^ ((r >> 1) & 3)) << 3;

    const int aBase = (wr * 128 + r) * 32 + sw8;          // elems within buffer
    const int bBase = 8192 + (wc * 64 + r) * 32 + sw8;

    // staging: thread covers one 16B slot per region; regions: A-lo,A-hi,B-lo,B-hi
    const int srow = tid >> 2;                            // 0..127 within region
    const int sg   = (((tid & 3) ^ ((srow >> 1) & 3)) << 3);  // pre-swizzled source granule
    const unsigned short* gA0 = A  + (size_t)(m0 + srow      ) * K_ + sg;
    const unsigned short* gA1 = A  + (size_t)(m0 + 128 + srow) * K_ + sg;
    const unsigned short* gB0 = Bt + (size_t)(n0 + srow      ) * K_ + sg;
    const unsigned short* gB1 = Bt + (size_t)(n0 + 128 + srow) * K_ + sg;
    unsigned short* const stw0 = sm + w * 512;            // buf0 staging base
    unsigned short* const stw1 = sm + 16384 + w * 512;    // buf1 staging base
    const unsigned short* const Sb0 = sm;                 // buf0 read base
    const unsigned short* const Sb1 = sm + 16384;         // buf1 read base

    floatx4 acc[8][4];
    #pragma unroll
    for (int i = 0; i < 8; ++i)
        #pragma unroll
        for (int j = 0; j < 4; ++j)
            #pragma unroll
            for (int e = 0; e < 4; ++e) acc[i][j][e] = 0.f;

    bf16x8 aqA[8], bqA[4], aqB[8], bqB[4];

    // prologue: stage tiles 0,1; drain; read tile-0 frags -> setA; fence
    STAGE(stw0, 0);
    STAGE(stw1, 32);
    asm volatile("s_waitcnt vmcnt(0)" ::: "memory");
    BARRIER();
    READ_FRAGS(Sb0, aqA, bqA);
    asm volatile("s_waitcnt lgkmcnt(0)" ::: "memory");
    BARRIER();

    // main loop: bodies for tiles 0..125 (even/odd pairs); tiles 126,127 peeled
    for (int tt = 0; tt < 63; ++tt) {
        // even body: tile e=2tt (setA); read e+1 (buf1 -> setB); stage e+2 -> buf0
        STAGE(stw0, 64 * tt + 64);
        READ_FRAGS(Sb1, aqB, bqB);
        __builtin_amdgcn_s_setprio(1);
        MFMA_ALL(aqA, bqA);
        __builtin_amdgcn_s_setprio(0);
        PIN_SCHED();
        BODY_WAITS();

        // odd body: tile o=2tt+1 (setB); read o+1 (buf0 -> setA); stage o+2 -> buf1
        STAGE(stw1, 64 * tt + 96);
        READ_FRAGS(Sb0, aqA, bqA);
        __builtin_amdgcn_s_setprio(1);
        MFMA_ALL(aqB, bqB);
        __builtin_amdgcn_s_setprio(0);
        PIN_SCHED();
        BODY_WAITS();
    }

    // tail: tile 126 frags already in setA (read in odd body tt=62);
    // tile 127 staged in that body (vmcnt0+barrier passed) -> read now.
    READ_FRAGS(Sb1, aqB, bqB);
    __builtin_amdgcn_s_setprio(1);
    MFMA_ALL(aqA, bqA);   // tile 126
    MFMA_ALL(aqB, bqB);   // tile 127 (compiler inserts lgkm wait)
    __builtin_amdgcn_s_setprio(0);

    // epilogue: C/D layout col = lane&15, row = quad*4 + reg  [m89/m91 verified]
    #pragma unroll
    for (int i = 0; i < 8; ++i) {
        #pragma unroll
        for (int j = 0; j < 4; ++j) {
            const int col = n0 + wc * 64 + j * 16 + r;
            #pragma unroll
            for (int e = 0; e < 4; ++e) {
                const int row = m0 + wr * 128 + i * 16 + quad * 4 + e;
                Z[(size_t)row * N_ + col] = f2bf(acc[i][j][e]);
            }
        }
    }
}

// ---------------------------------------------------------------------------
// Kernel 4: gate fusion. Reads Z(bf16), c, biases; writes h_new, c_new (fp32)
// ---------------------------------------------------------------------------
__global__ void k_gates(const unsigned short* __restrict__ Z, const float* __restrict__ c,
                        const float* __restrict__ bfp, const float* __restrict__ bip,
                        const float* __restrict__ bop, const float* __restrict__ bgp,
                        float* __restrict__ hout, float* __restrict__ cout) {
    int t = blockIdx.x * blockDim.x + threadIdx.x;   // 4 u-values each
    long e = (long)t * 4;
    int b = (int)(e >> 11);      // / 2048
    int u = (int)(e & 2047);
    const size_t zr = (size_t)b * N_;
    ushort4 zf4 = *(const ushort4*)(Z + zr + u);
    ushort4 zi4 = *(const ushort4*)(Z + zr + U_ + u);
    ushort4 zo4 = *(const ushort4*)(Z + zr + 2 * U_ + u);
    ushort4 zg4 = *(const ushort4*)(Z + zr + 3 * U_ + u);
    float4 bfv = *(const float4*)(bfp + u);
    float4 biv = *(const float4*)(bip + u);
    float4 bov = *(const float4*)(bop + u);
    float4 bgv = *(const float4*)(bgp + u);
    float4 cv  = *(const float4*)(c + e);

    float zf[4] = {bf2f(zf4.x), bf2f(zf4.y), bf2f(zf4.z), bf2f(zf4.w)};
    float zi[4] = {bf2f(zi4.x), bf2f(zi4.y), bf2f(zi4.z), bf2f(zi4.w)};
    float zo[4] = {bf2f(zo4.x), bf2f(zo4.y), bf2f(zo4.z), bf2f(zo4.w)};
    float zg[4] = {bf2f(zg4.x), bf2f(zg4.y), bf2f(zg4.z), bf2f(zg4.w)};
    float bff[4] = {bfv.x, bfv.y, bfv.z, bfv.w};
    float bif[4] = {biv.x, biv.y, biv.z, biv.w};
    float bof[4] = {bov.x, bov.y, bov.z, bov.w};
    float bgf[4] = {bgv.x, bgv.y, bgv.z, bgv.w};
    float cf[4]  = {cv.x, cv.y, cv.z, cv.w};

    float hh[4], cc[4];
    #pragma unroll
    for (int q = 0; q < 4; ++q) {
        float f = sigmoid_(zf[q] + bff[q]);
        float i = sigmoid_(zi[q] + bif[q]);
        float o = sigmoid_(zo[q] + bof[q]);
        float g = tanh_(zg[q] + bgf[q]);
        float cn = f * cf[q] + i * g;
        cc[q] = cn;
        hh[q] = o * tanh_(cn);
    }
    float4 ho, co;
    ho.x = hh[0]; ho.y = hh[1]; ho.z = hh[2]; ho.w = hh[3];
    co.x = cc[0]; co.y = cc[1]; co.z = cc[2]; co.w = cc[3];
    *(float4*)(hout + e) = ho;
    *(float4*)(cout + e) = co;
}

// ---------------------------------------------------------------------------
extern "C" void kernel_launch(void* const* d_in, const int* in_sizes, int n_in,
                              void* d_out, int out_size, void* d_ws, size_t ws_size,
                              hipStream_t stream) {
    const float* x   = (const float*)d_in[0];
    const float* h   = (const float*)d_in[1];
    const float* c   = (const float*)d_in[2];
    const float* Wxf = (const float*)d_in[3];
    const float* Wxi = (const float*)d_in[4];
    const float* Wxo = (const float*)d_in[5];
    const float* Wxg = (const float*)d_in[6];
    const float* bf  = (const float*)d_in[7];
    const float* bi  = (const float*)d_in[8];
    const float* bo  = (const float*)d_in[9];
    const float* bg  = (const float*)d_in[10];
    const float* Whf = (const float*)d_in[11];
    const float* Whi = (const float*)d_in[12];
    const float* Who = (const float*)d_in[13];
    const float* Whg = (const float*)d_in[14];
    float* out = (float*)d_out;

    // workspace layout: Abf (33.5 MB) | Bt (67 MB) | Z bf16 (67 MB)
    unsigned short* Abf = (unsigned short*)d_ws;
    unsigned short* Bt  = Abf + (size_t)B_ * K_;
    unsigned short* Z   = Bt + (size_t)N_ * K_;

    k_convA<<<(B_ * K_ / 4) / 256, 256, 0, stream>>>(x, h, Abf);
    k_convB<<<dim3(K_ / 64, U_ / 64, 4), 256, 0, stream>>>(
        Wxf, Wxi, Wxo, Wxg, Whf, Whi, Who, Whg, Bt);
    k_gemm<<<dim3((B_ / 256) * (N_ / 256)), 512, 0, stream>>>(Abf, Bt, Z);
    k_gates<<<(B_ * U_ / 4) / 256, 256, 0, stream>>>(
        Z, c, bf, bi, bo, bg, out, out + (size_t)B_ * U_);
}

// Round 11
// 493.827 us; speedup vs baseline: 1.0539x; 1.0539x over previous
//
#include <hip/hip_runtime.h>
#include <hip/hip_bf16.h>
#include <stdint.h>

#define B_ 4096
#define D_ 2048
#define U_ 2048
#define K_ 4096   // D + U
#define N_ 8192   // 4 * U

typedef __bf16 bf16x8 __attribute__((ext_vector_type(8)));
typedef float floatx4 __attribute__((ext_vector_type(4)));
typedef unsigned short ushort8 __attribute__((ext_vector_type(8)));

__device__ __forceinline__ unsigned short f2bf(float f) {
    union { float f; unsigned int u; } v; v.f = f;
    unsigned int u = v.u;
    unsigned int r = (u + 0x7fffu + ((u >> 16) & 1u)) >> 16;  // round-nearest-even
    return (unsigned short)r;
}

__device__ __forceinline__ float sigmoid_(float x) {
    return 1.0f / (1.0f + __expf(-x));
}
__device__ __forceinline__ float tanh_(float x) {
    return 1.0f - 2.0f / (__expf(2.0f * x) + 1.0f);
}

// ---------------------------------------------------------------------------
// Kernel 1: pack [x | h] -> Abf[4096][4096] bf16 (row-major, K contiguous)
// ---------------------------------------------------------------------------
__global__ void k_convA(const float* __restrict__ x, const float* __restrict__ h,
                        unsigned short* __restrict__ Abf) {
    int t = blockIdx.x * blockDim.x + threadIdx.x;   // one float4 each
    long e = (long)t * 4;
    int b = (int)(e >> 12);       // / 4096
    int k = (int)(e & 4095);
    const float* src = (k < D_) ? (x + (size_t)b * D_ + k)
                                : (h + (size_t)b * U_ + (k - D_));
    float4 v = *(const float4*)src;
    ushort4 o;
    o.x = f2bf(v.x); o.y = f2bf(v.y); o.z = f2bf(v.z); o.w = f2bf(v.w);
    *(ushort4*)(Abf + e) = o;
}

// ---------------------------------------------------------------------------
// Kernel 2: transpose weights -> Bt[8192][4096] bf16 (plain: row = g*2048+u)
// ---------------------------------------------------------------------------
__global__ __launch_bounds__(256) void k_convB(
        const float* __restrict__ Wx0, const float* __restrict__ Wx1,
        const float* __restrict__ Wx2, const float* __restrict__ Wx3,
        const float* __restrict__ Wh0, const float* __restrict__ Wh1,
        const float* __restrict__ Wh2, const float* __restrict__ Wh3,
        unsigned short* __restrict__ Bt) {
    __shared__ float tile[64][65];   // +1 pad: <=2-way (free) conflicts
    const int g  = blockIdx.z;
    const int k0 = blockIdx.x * 64;
    const int u0 = blockIdx.y * 64;
    const int t  = threadIdx.x;
    const float* W;
    if (k0 < D_) {
        W = (g == 0 ? Wx0 : g == 1 ? Wx1 : g == 2 ? Wx2 : Wx3) + (size_t)k0 * U_;
    } else {
        W = (g == 0 ? Wh0 : g == 1 ? Wh1 : g == 2 ? Wh2 : Wh3) + (size_t)(k0 - D_) * U_;
    }
    {
        const int kr_b = t >> 4;          // 0..15
        const int uc   = (t & 15) * 4;    // 0..60
        #pragma unroll
        for (int p = 0; p < 4; ++p) {
            int kr = p * 16 + kr_b;
            float4 v = *(const float4*)(W + (size_t)kr * U_ + u0 + uc);
            tile[kr][uc + 0] = v.x;
            tile[kr][uc + 1] = v.y;
            tile[kr][uc + 2] = v.z;
            tile[kr][uc + 3] = v.w;
        }
    }
    __syncthreads();
    {
        const int kc = (t & 7) * 8;       // 0..56
        #pragma unroll
        for (int p = 0; p < 2; ++p) {
            int u_idx = p * 32 + (t >> 3);          // 0..63
            int u = u0 + u_idx;
            int nrow = g * U_ + u;                   // plain mapping
            ushort8 o;
            #pragma unroll
            for (int kk = 0; kk < 8; ++kk)
                o[kk] = f2bf(tile[kc + kk][u_idx]);
            *(ushort8*)(Bt + (size_t)nrow * K_ + k0 + kc) = o;
        }
    }
}

// ---------------------------------------------------------------------------
// Kernel 3: FUSED GEMM+GATES. R10: K-loop reverted to R8's proven single-phase
// (240 µs, best measured; R9's frag-dbuf gained nothing). N-decomposition
// remapped: block = 256 b-rows x (64 u-cols x ALL 4 gates); wave B-frag j =
// gate j (Bt rows j*2048 + u0 + wc*16 + r). Lane-local acc[i][0..3][e] =
// z_f,z_i,z_o,z_g for the SAME (row,u) -> gate fusion is per-lane register
// math; writes h,c directly. Z buffer and k_gates ELIMINATED (-134 MB HBM
// + one launch); c-read moves into the compute-bound GEMM (free BW).
// T2 swizzle (conflicts 0, R7-verified), T5 setprio, T1 XCD swizzle kept.
// ---------------------------------------------------------------------------
__device__ __forceinline__ void gload16(const unsigned short* g, unsigned short* l) {
    __builtin_amdgcn_global_load_lds(
        (const __attribute__((address_space(1))) void*)g,
        (__attribute__((address_space(3))) void*)l, 16, 0, 0);
}

#define BARRIER() __builtin_amdgcn_s_barrier()

__global__ __launch_bounds__(512, 2) void k_gemm(const unsigned short* __restrict__ A,
                                                 const unsigned short* __restrict__ Bt,
                                                 const float* __restrict__ cvec,
                                                 const float* __restrict__ bfp,
                                                 const float* __restrict__ bip,
                                                 const float* __restrict__ bop,
                                                 const float* __restrict__ bgp,
                                                 float* __restrict__ hout,
                                                 float* __restrict__ cout) {
    __shared__ __align__(16) unsigned short sm[3 * 16384];   // 96 KB: 3-ring

    // T1: XCD-contiguous chunks; nwg=512, divisible by 8 -> simple swizzle valid
    const int id  = blockIdx.x;
    const int swz = (id & 7) * 64 + (id >> 3);
    const int m0  = (swz & 15) << 8;              // 16 m-blocks (256 rows)
    const int u0  = (swz >> 4) << 6;              // 32 u-blocks (64 u-cols)

    const int tid  = threadIdx.x;
    const int w    = tid >> 6;        // wave 0..7
    const int l    = tid & 63;
    const int wr   = w >> 2;          // 0..1  (M half)
    const int wc   = w & 3;           // 0..3  (u sixteenth)
    const int r    = l & 15;
    const int quad = l >> 4;
    // T2 read-side swizzle: granule' = quad ^ ((row>>1)&3); all row bases are
    // 4-aligned so (row>>1)&3 == (r>>1)&3 — per-lane constant. (B rows
    // j*64+wc*16+r: j*64,wc*16 both 4-aligned ✓)
    const int sw8  = (quad ^ ((r >> 1) & 3)) << 3;

    const int aBase = (wr * 128 + r) * 32 + sw8;          // elems within buffer
    const int bBase = 8192 + (wc * 16 + r) * 32 + sw8;    // + j*2048 per gate-frag

    // staging: thread covers one 16B slot per region; regions: A-lo,A-hi,B-lo,B-hi
    // B LDS rows 0..255 = gate-major: row = g*64 + (u-u0)
    const int srow = tid >> 2;                            // 0..127 within region
    const int sg   = (((tid & 3) ^ ((srow >> 1) & 3)) << 3);  // pre-swizzled source granule
    const unsigned short* gA0 = A + (size_t)(m0 + srow      ) * K_ + sg;
    const unsigned short* gA1 = A + (size_t)(m0 + 128 + srow) * K_ + sg;
    // B-lo: gates 0,1 ; B-hi: gates 2,3   (row_g = gate*2048 + u0 + (srow&63))
    const unsigned short* gB0 = Bt + (size_t)(((srow >> 6)    ) * U_ + u0 + (srow & 63)) * K_ + sg;
    const unsigned short* gB1 = Bt + (size_t)(((srow >> 6) + 2) * U_ + u0 + (srow & 63)) * K_ + sg;
    unsigned short* const stw = sm + w * 512;   // + buf*16384 + region*4096; HW adds lane*16B

    floatx4 acc[8][4];
    #pragma unroll
    for (int i = 0; i < 8; ++i)
        #pragma unroll
        for (int j = 0; j < 4; ++j)
            #pragma unroll
            for (int e = 0; e < 4; ++e) acc[i][j][e] = 0.f;

    // prologue: stage tiles 0,1 into bufs 0,1; wait tile 0 (vmcnt 8 -> 4)
    #pragma unroll
    for (int tt = 0; tt < 2; ++tt) {
        unsigned short* b = stw + tt * 16384;
        const int kt = tt * 32;
        gload16(gA0 + kt, b);
        gload16(gA1 + kt, b + 4096);
        gload16(gB0 + kt, b + 8192);
        gload16(gB1 + kt, b + 12288);
    }
    asm volatile("s_waitcnt vmcnt(4)" ::: "memory");
    BARRIER();

    int c = 0;
    for (int t = 0; t < 128; ++t) {
        const unsigned short* Sb = sm + c * 16384;
        const int cst = (c == 0) ? 2 : c - 1;             // == (t+2)%3
        unsigned short* sb = stw + cst * 16384;
        const int kt = (t + 2) * 32;
        const bool st = (t < 126);

        // ---- single phase: all fragment reads, then stage, then 32 MFMA ----
        bf16x8 bq[4], aq[8];
        #pragma unroll
        for (int j = 0; j < 4; ++j) bq[j] = *(const bf16x8*)(Sb + bBase + j * 2048);
        #pragma unroll
        for (int i = 0; i < 8; ++i) aq[i] = *(const bf16x8*)(Sb + aBase + i * 512);
        if (st) {
            gload16(gA0 + kt, sb);
            gload16(gA1 + kt, sb + 4096);
            gload16(gB0 + kt, sb + 8192);
            gload16(gB1 + kt, sb + 12288);
        }
        __builtin_amdgcn_s_setprio(1);
        #pragma unroll
        for (int i = 0; i < 8; ++i)
            #pragma unroll
            for (int j = 0; j < 4; ++j)
                acc[i][j] = __builtin_amdgcn_mfma_f32_16x16x32_bf16(
                    aq[i], bq[j], acc[i][j], 0, 0, 0);
        __builtin_amdgcn_s_setprio(0);
        // boundary: counted vmcnt BEFORE barrier (cross-wave visibility chain)
        if (st) asm volatile("s_waitcnt vmcnt(4)" ::: "memory");
        else    asm volatile("s_waitcnt vmcnt(0)" ::: "memory");
        BARRIER();

        c = (c == 2) ? 0 : c + 1;
    }

    // fused epilogue: acc[i][gate][e] all gates lane-local for (row, u).
    // C/D layout col = lane&15, row = quad*4 + reg  [m89/m91 verified]
    const int u = u0 + wc * 16 + r;
    const float bfv = bfp[u], biv = bip[u], bov = bop[u], bgv = bgp[u];
    #pragma unroll
    for (int i = 0; i < 8; ++i) {
        #pragma unroll
        for (int e = 0; e < 4; ++e) {
            const int row = m0 + wr * 128 + i * 16 + quad * 4 + e;
            const size_t cu = (size_t)row * U_ + u;
            float f  = sigmoid_(acc[i][0][e] + bfv);
            float ig = sigmoid_(acc[i][1][e] + biv);
            float o  = sigmoid_(acc[i][2][e] + bov);
            float g  = tanh_(acc[i][3][e] + bgv);
            float cn = f * cvec[cu] + ig * g;
            hout[cu] = o * tanh_(cn);
            cout[cu] = cn;
        }
    }
}

// ---------------------------------------------------------------------------
extern "C" void kernel_launch(void* const* d_in, const int* in_sizes, int n_in,
                              void* d_out, int out_size, void* d_ws, size_t ws_size,
                              hipStream_t stream) {
    const float* x   = (const float*)d_in[0];
    const float* h   = (const float*)d_in[1];
    const float* c   = (const float*)d_in[2];
    const float* Wxf = (const float*)d_in[3];
    const float* Wxi = (const float*)d_in[4];
    const float* Wxo = (const float*)d_in[5];
    const float* Wxg = (const float*)d_in[6];
    const float* bf  = (const float*)d_in[7];
    const float* bi  = (const float*)d_in[8];
    const float* bo  = (const float*)d_in[9];
    const float* bg  = (const float*)d_in[10];
    const float* Whf = (const float*)d_in[11];
    const float* Whi = (const float*)d_in[12];
    const float* Who = (const float*)d_in[13];
    const float* Whg = (const float*)d_in[14];
    float* out = (float*)d_out;

    // workspace layout: Abf (33.5 MB) | Bt (134 MB)   (Z eliminated)
    unsigned short* Abf = (unsigned short*)d_ws;
    unsigned short* Bt  = Abf + (size_t)B_ * K_;

    k_convA<<<(B_ * K_ / 4) / 256, 256, 0, stream>>>(x, h, Abf);
    k_convB<<<dim3(K_ / 64, U_ / 64, 4), 256, 0, stream>>>(
        Wxf, Wxi, Wxo, Wxg, Whf, Whi, Who, Whg, Bt);
    k_gemm<<<dim3((B_ / 256) * (U_ / 64)), 512, 0, stream>>>(
        Abf, Bt, c, bf, bi, bo, bg, out, out + (size_t)B_ * U_);
}

// Round 12
// 488.249 us; speedup vs baseline: 1.0660x; 1.0114x over previous
//
#include <hip/hip_runtime.h>
#include <hip/hip_bf16.h>
#include <stdint.h>

#define B_ 4096
#define D_ 2048
#define U_ 2048
#define K_ 4096   // D + U
#define N_ 8192   // 4 * U

typedef __bf16 bf16x8 __attribute__((ext_vector_type(8)));
typedef float floatx4 __attribute__((ext_vector_type(4)));
typedef unsigned short ushort8 __attribute__((ext_vector_type(8)));

__device__ __forceinline__ unsigned short f2bf(float f) {
    union { float f; unsigned int u; } v; v.f = f;
    unsigned int u = v.u;
    unsigned int r = (u + 0x7fffu + ((u >> 16) & 1u)) >> 16;  // round-nearest-even
    return (unsigned short)r;
}

__device__ __forceinline__ float sigmoid_(float x) {
    return 1.0f / (1.0f + __expf(-x));
}
__device__ __forceinline__ float tanh_(float x) {
    return 1.0f - 2.0f / (__expf(2.0f * x) + 1.0f);
}

// ---------------------------------------------------------------------------
// Kernel 1 (R12: MERGED convA+convB — one launch, concurrent execution).
// bids [0, 8192): convB unit — transpose weights into Bt[8192][4096] bf16.
// bids [8192, 24576): convA unit — pack [x|h] -> Abf[4096][4096] bf16.
// Internals of both paths byte-identical to the R11 kernels; convA's
// streaming blocks fill HBM BW while convB blocks sit in LDS/sync phases.
// ---------------------------------------------------------------------------
__global__ __launch_bounds__(256) void k_conv(
        const float* __restrict__ x, const float* __restrict__ h,
        unsigned short* __restrict__ Abf,
        const float* __restrict__ Wx0, const float* __restrict__ Wx1,
        const float* __restrict__ Wx2, const float* __restrict__ Wx3,
        const float* __restrict__ Wh0, const float* __restrict__ Wh1,
        const float* __restrict__ Wh2, const float* __restrict__ Wh3,
        unsigned short* __restrict__ Bt) {
    __shared__ float tile[64][65];   // convB path only; +1 pad
    const int bid = blockIdx.x;
    if (bid >= 8192) {
        // ---- convA path: one float4 per thread ----
        int t = (bid - 8192) * 256 + threadIdx.x;
        long e = (long)t * 4;
        int b = (int)(e >> 12);       // / 4096
        int k = (int)(e & 4095);
        const float* src = (k < D_) ? (x + (size_t)b * D_ + k)
                                    : (h + (size_t)b * U_ + (k - D_));
        float4 v = *(const float4*)src;
        ushort4 o;
        o.x = f2bf(v.x); o.y = f2bf(v.y); o.z = f2bf(v.z); o.w = f2bf(v.w);
        *(ushort4*)(Abf + e) = o;
        return;
    }
    // ---- convB path: 64x64 transpose tile ----
    const int g    = bid & 3;
    const int rest = bid >> 2;
    const int u0   = (rest & 31) << 6;
    const int k0   = (rest >> 5) << 6;
    const int t    = threadIdx.x;
    const float* W;
    if (k0 < D_) {
        W = (g == 0 ? Wx0 : g == 1 ? Wx1 : g == 2 ? Wx2 : Wx3) + (size_t)k0 * U_;
    } else {
        W = (g == 0 ? Wh0 : g == 1 ? Wh1 : g == 2 ? Wh2 : Wh3) + (size_t)(k0 - D_) * U_;
    }
    {
        const int kr_b = t >> 4;          // 0..15
        const int uc   = (t & 15) * 4;    // 0..60
        #pragma unroll
        for (int p = 0; p < 4; ++p) {
            int kr = p * 16 + kr_b;
            float4 v = *(const float4*)(W + (size_t)kr * U_ + u0 + uc);
            tile[kr][uc + 0] = v.x;
            tile[kr][uc + 1] = v.y;
            tile[kr][uc + 2] = v.z;
            tile[kr][uc + 3] = v.w;
        }
    }
    __syncthreads();
    {
        const int kc = (t & 7) * 8;       // 0..56
        #pragma unroll
        for (int p = 0; p < 2; ++p) {
            int u_idx = p * 32 + (t >> 3);          // 0..63
            int u = u0 + u_idx;
            int nrow = g * U_ + u;                   // plain mapping
            ushort8 o;
            #pragma unroll
            for (int kk = 0; kk < 8; ++kk)
                o[kk] = f2bf(tile[kc + kk][u_idx]);
            *(ushort8*)(Bt + (size_t)nrow * K_ + k0 + kc) = o;
        }
    }
}

// ---------------------------------------------------------------------------
// Kernel 2: FUSED GEMM+GATES (byte-identical to R11's measured 260 µs).
// Block = 256 b-rows x (64 u-cols x 4 gates); wave B-frag j = gate j.
// Lane-local acc[i][0..3][e] = z_f,z_i,z_o,z_g for same (row,u); writes
// h,c directly. R8 single-phase K-loop, 3-ring, counted vmcnt, T1/T2/T5.
// Per-tile ledger (R11): 2437 cyc = LDS 128KB r+w (~1190) + MFMA (1242),
// serial — LDS-traffic wall; 1-wave/SIMD rebuild deferred.
// ---------------------------------------------------------------------------
__device__ __forceinline__ void gload16(const unsigned short* g, unsigned short* l) {
    __builtin_amdgcn_global_load_lds(
        (const __attribute__((address_space(1))) void*)g,
        (__attribute__((address_space(3))) void*)l, 16, 0, 0);
}

#define BARRIER() __builtin_amdgcn_s_barrier()

__global__ __launch_bounds__(512, 2) void k_gemm(const unsigned short* __restrict__ A,
                                                 const unsigned short* __restrict__ Bt,
                                                 const float* __restrict__ cvec,
                                                 const float* __restrict__ bfp,
                                                 const float* __restrict__ bip,
                                                 const float* __restrict__ bop,
                                                 const float* __restrict__ bgp,
                                                 float* __restrict__ hout,
                                                 float* __restrict__ cout) {
    __shared__ __align__(16) unsigned short sm[3 * 16384];   // 96 KB: 3-ring

    // T1: XCD-contiguous chunks; nwg=512, divisible by 8 -> simple swizzle valid
    const int id  = blockIdx.x;
    const int swz = (id & 7) * 64 + (id >> 3);
    const int m0  = (swz & 15) << 8;              // 16 m-blocks (256 rows)
    const int u0  = (swz >> 4) << 6;              // 32 u-blocks (64 u-cols)

    const int tid  = threadIdx.x;
    const int w    = tid >> 6;        // wave 0..7
    const int l    = tid & 63;
    const int wr   = w >> 2;          // 0..1  (M half)
    const int wc   = w & 3;           // 0..3  (u sixteenth)
    const int r    = l & 15;
    const int quad = l >> 4;
    // T2 read-side swizzle: granule' = quad ^ ((row>>1)&3); all row bases are
    // 4-aligned so (row>>1)&3 == (r>>1)&3 — per-lane constant.
    const int sw8  = (quad ^ ((r >> 1) & 3)) << 3;

    const int aBase = (wr * 128 + r) * 32 + sw8;          // elems within buffer
    const int bBase = 8192 + (wc * 16 + r) * 32 + sw8;    // + j*2048 per gate-frag

    // staging: thread covers one 16B slot per region; regions: A-lo,A-hi,B-lo,B-hi
    // B LDS rows 0..255 = gate-major: row = g*64 + (u-u0)
    const int srow = tid >> 2;                            // 0..127 within region
    const int sg   = (((tid & 3) ^ ((srow >> 1) & 3)) << 3);  // pre-swizzled source granule
    const unsigned short* gA0 = A + (size_t)(m0 + srow      ) * K_ + sg;
    const unsigned short* gA1 = A + (size_t)(m0 + 128 + srow) * K_ + sg;
    // B-lo: gates 0,1 ; B-hi: gates 2,3   (row_g = gate*2048 + u0 + (srow&63))
    const unsigned short* gB0 = Bt + (size_t)(((srow >> 6)    ) * U_ + u0 + (srow & 63)) * K_ + sg;
    const unsigned short* gB1 = Bt + (size_t)(((srow >> 6) + 2) * U_ + u0 + (srow & 63)) * K_ + sg;
    unsigned short* const stw = sm + w * 512;   // + buf*16384 + region*4096; HW adds lane*16B

    floatx4 acc[8][4];
    #pragma unroll
    for (int i = 0; i < 8; ++i)
        #pragma unroll
        for (int j = 0; j < 4; ++j)
            #pragma unroll
            for (int e = 0; e < 4; ++e) acc[i][j][e] = 0.f;

    // prologue: stage tiles 0,1 into bufs 0,1; wait tile 0 (vmcnt 8 -> 4)
    #pragma unroll
    for (int tt = 0; tt < 2; ++tt) {
        unsigned short* b = stw + tt * 16384;
        const int kt = tt * 32;
        gload16(gA0 + kt, b);
        gload16(gA1 + kt, b + 4096);
        gload16(gB0 + kt, b + 8192);
        gload16(gB1 + kt, b + 12288);
    }
    asm volatile("s_waitcnt vmcnt(4)" ::: "memory");
    BARRIER();

    int c = 0;
    for (int t = 0; t < 128; ++t) {
        const unsigned short* Sb = sm + c * 16384;
        const int cst = (c == 0) ? 2 : c - 1;             // == (t+2)%3
        unsigned short* sb = stw + cst * 16384;
        const int kt = (t + 2) * 32;
        const bool st = (t < 126);

        // ---- single phase: all fragment reads, then stage, then 32 MFMA ----
        bf16x8 bq[4], aq[8];
        #pragma unroll
        for (int j = 0; j < 4; ++j) bq[j] = *(const bf16x8*)(Sb + bBase + j * 2048);
        #pragma unroll
        for (int i = 0; i < 8; ++i) aq[i] = *(const bf16x8*)(Sb + aBase + i * 512);
        if (st) {
            gload16(gA0 + kt, sb);
            gload16(gA1 + kt, sb + 4096);
            gload16(gB0 + kt, sb + 8192);
            gload16(gB1 + kt, sb + 12288);
        }
        __builtin_amdgcn_s_setprio(1);
        #pragma unroll
        for (int i = 0; i < 8; ++i)
            #pragma unroll
            for (int j = 0; j < 4; ++j)
                acc[i][j] = __builtin_amdgcn_mfma_f32_16x16x32_bf16(
                    aq[i], bq[j], acc[i][j], 0, 0, 0);
        __builtin_amdgcn_s_setprio(0);
        // boundary: counted vmcnt BEFORE barrier (cross-wave visibility chain)
        if (st) asm volatile("s_waitcnt vmcnt(4)" ::: "memory");
        else    asm volatile("s_waitcnt vmcnt(0)" ::: "memory");
        BARRIER();

        c = (c == 2) ? 0 : c + 1;
    }

    // fused epilogue: acc[i][gate][e] all gates lane-local for (row, u).
    // C/D layout col = lane&15, row = quad*4 + reg  [m89/m91 verified]
    const int u = u0 + wc * 16 + r;
    const float bfv = bfp[u], biv = bip[u], bov = bop[u], bgv = bgp[u];
    #pragma unroll
    for (int i = 0; i < 8; ++i) {
        #pragma unroll
        for (int e = 0; e < 4; ++e) {
            const int row = m0 + wr * 128 + i * 16 + quad * 4 + e;
            const size_t cu = (size_t)row * U_ + u;
            float f  = sigmoid_(acc[i][0][e] + bfv);
            float ig = sigmoid_(acc[i][1][e] + biv);
            float o  = sigmoid_(acc[i][2][e] + bov);
            float g  = tanh_(acc[i][3][e] + bgv);
            float cn = f * cvec[cu] + ig * g;
            hout[cu] = o * tanh_(cn);
            cout[cu] = cn;
        }
    }
}

// ---------------------------------------------------------------------------
extern "C" void kernel_launch(void* const* d_in, const int* in_sizes, int n_in,
                              void* d_out, int out_size, void* d_ws, size_t ws_size,
                              hipStream_t stream) {
    const float* x   = (const float*)d_in[0];
    const float* h   = (const float*)d_in[1];
    const float* c   = (const float*)d_in[2];
    const float* Wxf = (const float*)d_in[3];
    const float* Wxi = (const float*)d_in[4];
    const float* Wxo = (const float*)d_in[5];
    const float* Wxg = (const float*)d_in[6];
    const float* bf  = (const float*)d_in[7];
    const float* bi  = (const float*)d_in[8];
    const float* bo  = (const float*)d_in[9];
    const float* bg  = (const float*)d_in[10];
    const float* Whf = (const float*)d_in[11];
    const float* Whi = (const float*)d_in[12];
    const float* Who = (const float*)d_in[13];
    const float* Whg = (const float*)d_in[14];
    float* out = (float*)d_out;

    // workspace layout: Abf (33.5 MB) | Bt (134 MB)
    unsigned short* Abf = (unsigned short*)d_ws;
    unsigned short* Bt  = Abf + (size_t)B_ * K_;

    k_conv<<<8192 + 16384, 256, 0, stream>>>(
        x, h, Abf, Wxf, Wxi, Wxo, Wxg, Whf, Whi, Who, Whg, Bt);
    k_gemm<<<dim3((B_ / 256) * (U_ / 64)), 512, 0, stream>>>(
        Abf, Bt, c, bf, bi, bo, bg, out, out + (size_t)B_ * U_);
}